// Round 14
// baseline (23.351 us; speedup 1.0000x reference)
//
#include <hip/hip_runtime.h>
#include <stdint.h>

#define BATCH 16
#define NPIX 200704      // 448*448
#define EPS 1e-6f
#define FW 64            // fine grid == one 64x64 tile
#define NCHUNK 16        // pixel chunks per batch in K1
#define CHPX (NPIX / NCHUNK)     // 12544 pixels (u16-safe: < 65536)
#define CHF4 (CHPX / 4)          // 3136 float4 per plane
#define SLAB4 512                // uint4 per (b,chunk) slab: 64 rows x 8 uint4 (u16-packed)

// K(c,g) = 1 / (1 + ((cc - b_g)/sigma)^2), cc=(c+0.5)/FW, b_g=g/63, 1/sigma=50
__device__ __forceinline__ float kval(int c, int g) {
  float d = (((float)c + 0.5f) * (1.0f / (float)FW) - (float)g * (1.0f / 63.0f)) * 50.0f;
  return 1.0f / (1.0f + d * d);
}

// ---------------- K1: 64x64 u16 histogram per (batch, chunk) + T-partial ----------------
__global__ __launch_bounds__(1024) void hist64(const float* __restrict__ x,
                                               unsigned int* __restrict__ Hq,
                                               float* __restrict__ Tpart) {
  __shared__ unsigned int sh[2048];   // 4096 u16 bins (full 64x64 grid), packed
  __shared__ float sS[64];            // S(c) = sum_g K(c,g)
  __shared__ float sred[1024];
  const int bid = blockIdx.x;
  const int tid = threadIdx.x;
  const int xcd = bid & 7;            // batch pinned to XCD b%8
  const int t0 = bid >> 3;            // 0..31
  const int chunk = t0 & (NCHUNK - 1);
  const int b = xcd + 8 * (t0 >> 4);

  if (tid < 512) ((uint4*)sh)[tid] = make_uint4(0u, 0u, 0u, 0u);
  __syncthreads();

  const float* xb = x + (size_t)b * 3 * NPIX;
  const float4* R  = (const float4*)xb + (size_t)chunk * CHF4;
  const float4* G  = (const float4*)(xb + NPIX) + (size_t)chunk * CHF4;
  const float4* Bl = (const float4*)(xb + 2 * NPIX) + (size_t)chunk * CHF4;

  for (int t = tid; t < CHF4; t += 1024) {
    float4 rv = R[t], gv = G[t], bv = Bl[t];
    float rr[4] = {rv.x, rv.y, rv.z, rv.w};
    float gg[4] = {gv.x, gv.y, gv.z, gv.w};
    float bb[4] = {bv.x, bv.y, bv.z, bv.w};
#pragma unroll
    for (int c = 0; c < 4; c++) {
      float r  = fminf(fmaxf(rr[c], 0.0f), 1.0f);
      float g  = fminf(fmaxf(gg[c], 0.0f), 1.0f);
      float bl = fminf(fmaxf(bb[c], 0.0f), 1.0f);
      float inv = 1.0f / (r + g + bl + EPS);
      int i = min((int)(r * inv * (float)FW), FW - 1);
      int j = min((int)(g * inv * (float)FW), FW - 1);
      unsigned int id = (unsigned int)((i << 6) | j);
      atomicAdd(&sh[id >> 1], 1u << ((id & 1u) << 4));   // packed u16; <=12544 adds: safe
    }
  }
  // S table (fixed summation order, deterministic)
  if (tid < 64) {
    float s = 0.0f;
    for (int g = 0; g < 64; g++) s += kval(tid, g);
    sS[tid] = s;
  }
  __syncthreads();

  // T-partial: sum over all cells of cnt * S_i * S_j (fixed tree order)
  {
    float val = 0.0f;
#pragma unroll
    for (int rep = 0; rep < 2; rep++) {
      int w = rep * 1024 + tid;        // word: row i = w>>5, j pair = (w&31)*2
      unsigned int v = sh[w];
      int i = w >> 5, j0 = (w & 31) * 2;
      val += (float)(v & 0xFFFFu) * sS[i] * sS[j0]
           + (float)(v >> 16)     * sS[i] * sS[j0 + 1];
    }
    sred[tid] = val;
    __syncthreads();
    for (int st = 512; st > 0; st >>= 1) {
      if (tid < st) sred[tid] += sred[tid + st];
      __syncthreads();
    }
    if (tid == 0) Tpart[b * NCHUNK + chunk] = sred[0];
  }

  // flush packed tile
  if (tid < 512)
    ((uint4*)Hq)[(size_t)(b * NCHUNK + chunk) * SLAB4 + tid] = ((const uint4*)sh)[tid];
}

// ---------------- K2: chunk-sum -> M-strip GEMM -> K^T epilogue -> normalize -> out ----------------
// block (b, g-strip gs of 8 cols): M[i][gc] = sum_j Hsum[i][j]*K(j,g0+gc)
// out[b][r][g0+gc] = (sum_i K(i,r)*M[i][gc]) / (T_b + EPS)
__global__ __launch_bounds__(256) void bc_final(const unsigned int* __restrict__ Hq,
                                                const float* __restrict__ Tpart,
                                                float* __restrict__ out) {
  __shared__ float sH[64][68];   // Hsum (f32); overwritten by K_C after M-phase
  __shared__ float sKg[64][8];   // K(j, strip)
  __shared__ float sM[64][8];    // M strip
  const int bid = blockIdx.x;    // 128 = xcd(8) x gs(8) x bh(2)
  const int tid = threadIdx.x;
  const int xcd = bid & 7;
  const int gs = (bid >> 3) & 7;
  const int b = xcd + 8 * (bid >> 6);
  const int g0 = gs * 8;

  // ---- stage: sum 16 chunk tiles (packed u16 -> f32) ----
  {
    const uint4* Hb = (const uint4*)Hq + (size_t)b * NCHUNK * SLAB4;
#pragma unroll
    for (int rep = 0; rep < 2; rep++) {
      int t2 = rep * 256 + tid;        // 512 uint4 cells: row = t2>>3, c8 = t2&7
      int row = t2 >> 3, c8 = t2 & 7;
      unsigned int a0 = 0, a1 = 0, a2 = 0, a3 = 0, a4 = 0, a5 = 0, a6 = 0, a7 = 0;
#pragma unroll
      for (int ch = 0; ch < NCHUNK; ch++) {
        uint4 v = Hb[(size_t)ch * SLAB4 + row * 8 + c8];
        a0 += v.x & 0xFFFFu; a1 += v.x >> 16;
        a2 += v.y & 0xFFFFu; a3 += v.y >> 16;
        a4 += v.z & 0xFFFFu; a5 += v.z >> 16;
        a6 += v.w & 0xFFFFu; a7 += v.w >> 16;
      }
      int cc = c8 * 8;
      *(float4*)&sH[row][cc]     = make_float4((float)a0, (float)a1, (float)a2, (float)a3);
      *(float4*)&sH[row][cc + 4] = make_float4((float)a4, (float)a5, (float)a6, (float)a7);
    }
  }
  // K strip
#pragma unroll
  for (int rep = 0; rep < 2; rep++) {
    int idx = rep * 256 + tid;         // 512 = 64 j x 8 gc
    int j = idx >> 3, gc = idx & 7;
    sKg[j][gc] = kval(j, g0 + gc);
  }
  __syncthreads();

  // ---- M-phase: thread = (i-pair, gc) ----
  {
    int i2 = tid >> 3, gc = tid & 7;
    int ir = i2 * 2;
    float m0 = 0.0f, m1 = 0.0f;
#pragma unroll 4
    for (int jt = 0; jt < 16; jt++) {
      float4 h0 = *(const float4*)&sH[ir][jt * 4];
      float4 h1 = *(const float4*)&sH[ir + 1][jt * 4];
      float hh0[4] = {h0.x, h0.y, h0.z, h0.w};
      float hh1[4] = {h1.x, h1.y, h1.z, h1.w};
#pragma unroll
      for (int p = 0; p < 4; p++) {
        float kv = sKg[jt * 4 + p][gc];
        m0 = fmaf(hh0[p], kv, m0);
        m1 = fmaf(hh1[p], kv, m1);
      }
    }
    sM[ir][gc] = m0;
    sM[ir + 1][gc] = m1;
  }
  __syncthreads();

  // ---- K_C fill (overwrites sH; safe after sync) ----
#pragma unroll
  for (int rep = 0; rep < 16; rep++) {
    int idx = rep * 256 + tid;         // 4096 = 64 i x 64 r
    int i = idx >> 6, r = idx & 63;
    sH[i][r] = kval(i, r);
  }
  __syncthreads();

  // ---- epilogue + normalize + store: thread = (r, 2 g-cols) ----
  {
    int r = tid >> 2, gp = (tid & 3) * 2;
    float o0 = 0.0f, o1 = 0.0f;
#pragma unroll 8
    for (int i = 0; i < 64; i++) {
      float kc = sH[i][r];
      o0 = fmaf(kc, sM[i][gp], o0);
      o1 = fmaf(kc, sM[i][gp + 1], o1);
    }
    const float* tp = Tpart + b * NCHUNK;
    float T = 0.0f;
#pragma unroll
    for (int c = 0; c < NCHUNK; c++) T += tp[c];   // fixed order: deterministic
    float inv = 1.0f / (T + EPS);
    float* dst = out + (size_t)b * 4096 + r * 64 + g0 + gp;
    dst[0] = o0 * inv;
    dst[1] = o1 * inv;
  }
}

extern "C" void kernel_launch(void* const* d_in, const int* in_sizes, int n_in,
                              void* d_out, int out_size, void* d_ws, size_t ws_size,
                              hipStream_t stream) {
  const float* x = (const float*)d_in[0];
  float* out = (float*)d_out;

  char* p = (char*)d_ws;
  unsigned int* Hq = (unsigned int*)p;  p += (size_t)BATCH * NCHUNK * SLAB4 * 16;  // 2.1 MB
  float* Tpart = (float*)p;

  hist64<<<256, 1024, 0, stream>>>(x, Hq, Tpart);
  bc_final<<<128, 256, 0, stream>>>(Hq, Tpart, out);
}